// Round 1
// baseline (160.303 us; speedup 1.0000x reference)
//
#include <hip/hip_runtime.h>

// PixelVectorExtractor: x (32,16,128,128) f32 ->
// out (32, 16384, 17, 9) f32 where out[n][h*128+w][c][hl*3+wl] =
//   c==16 ? 1.0f : zero-padded x[n][c][h+hl-1][w+wl-1]

#define NN 32
#define CC 16
#define HH 128
#define WW 128

__global__ __launch_bounds__(256) void pve_kernel(const float* __restrict__ x,
                                                  float* __restrict__ out,
                                                  int n4) {
    int idx = blockIdx.x * blockDim.x + threadIdx.x;
    int stride = gridDim.x * blockDim.x;
    for (int q = idx; q < n4; q += stride) {
        float vals[4];
#pragma unroll
        for (int k = 0; k < 4; ++k) {
            unsigned i = 4u * (unsigned)q + (unsigned)k;
            // i = ((n*16384 + hw) * 17 + c) * 9 + p
            unsigned p = i % 9u;
            unsigned t = i / 9u;
            unsigned c = t % 17u;
            unsigned s = t / 17u;
            unsigned hw = s & 16383u;
            unsigned n = s >> 14;
            unsigned h = hw >> 7;
            unsigned w = hw & 127u;
            unsigned hl = p / 3u;
            unsigned wl = p % 3u;
            float val;
            if (c == 16u) {
                val = 1.0f;
            } else {
                int hh = (int)h + (int)hl - 1;
                int ww2 = (int)w + (int)wl - 1;
                bool ok = ((unsigned)hh < (unsigned)HH) && ((unsigned)ww2 < (unsigned)WW);
                unsigned src = (((n * CC + c) * HH + (unsigned)hh) * WW + (unsigned)ww2);
                val = ok ? x[src] : 0.0f;
            }
            vals[k] = val;
        }
        float4 v;
        v.x = vals[0];
        v.y = vals[1];
        v.z = vals[2];
        v.w = vals[3];
        reinterpret_cast<float4*>(out)[q] = v;
    }
}

extern "C" void kernel_launch(void* const* d_in, const int* in_sizes, int n_in,
                              void* d_out, int out_size, void* d_ws, size_t ws_size,
                              hipStream_t stream) {
    const float* x = (const float*)d_in[0];
    float* out = (float*)d_out;
    int n4 = out_size / 4;  // 20,054,016 float4 chunks
    int block = 256;
    int grid = 2048;
    pve_kernel<<<grid, block, 0, stream>>>(x, out, n4);
}

// Round 2
// 89.864 us; speedup vs baseline: 1.7838x; 1.7838x over previous
//
#include <hip/hip_runtime.h>

// PixelVectorExtractor: x (32,16,128,128) f32 ->
// out (32, 16384, 17, 9) f32 where out[n][h*128+w][c][hl*3+wl] =
//   c==16 ? 1.0f : zero-padded x[n][c][h+hl-1][w+wl-1]
//
// One block per (n, h): output slab is 128*17*9 = 19584 contiguous floats.
// Stage rows h-1,h,h+1 of all 16 channels in LDS with zero-padded halo.

#define NN 32
#define CC 16
#define HH 128
#define WW 128
// LDS row: 136 floats; data x[w] at [4+w] (16B-aligned), pads at [3] and [132]
#define LROW 136

__global__ __launch_bounds__(256) void pve_kernel(const float* __restrict__ x,
                                                  float* __restrict__ out) {
    __shared__ float lds[CC * 3 * LROW];  // 26112 B

    // bijective XCD swizzle: 4096 blocks, 8 XCDs, 512 contiguous per XCD
    unsigned bid = blockIdx.x;
    unsigned swz = (bid & 7u) * 512u + (bid >> 3);
    unsigned n = swz >> 7;        // image
    unsigned h = swz & 127u;      // output row
    unsigned tid = threadIdx.x;

    // zero the halo pad slots of all 48 (c,hl) rows
    if (tid < 48u) {
        lds[tid * LROW + 3] = 0.0f;
        lds[tid * LROW + 132] = 0.0f;
    }

    // stage: 48 rows (c major, hl minor) x 128 floats = 1536 float4, 6/thread
#pragma unroll
    for (int j = 0; j < 6; ++j) {
        unsigned li = tid + 256u * j;       // 0..1535
        unsigned row = li >> 5;             // 0..47 = c*3 + hl
        unsigned col = li & 31u;            // float4 column
        unsigned c = row / 3u;
        unsigned hl = row - c * 3u;
        int hh = (int)h + (int)hl - 1;
        float4 v = make_float4(0.f, 0.f, 0.f, 0.f);
        if ((unsigned)hh < (unsigned)HH) {
            v = reinterpret_cast<const float4*>(
                    x)[((n * CC + c) * HH + (unsigned)hh) * (WW / 4) + col];
        }
        *reinterpret_cast<float4*>(&lds[row * LROW + 4u + col * 4u]) = v;
    }
    __syncthreads();

    // write slab: 4896 float4, contiguous at (n*16384 + h*128) * 153
    unsigned base = (n * 16384u + h * 128u) * 153u;
    float4* outp = reinterpret_cast<float4*>(out + base);
#pragma unroll 2
    for (unsigned q = tid; q < 4896u; q += 256u) {
        unsigned i = q * 4u;
        float vals[4];
#pragma unroll
        for (int k = 0; k < 4; ++k) {
            unsigned ii = i + (unsigned)k;
            unsigned p = ii % 9u;           // patch pos: hl*3 + wl
            unsigned t = ii / 9u;           // = w*17 + c
            unsigned c = t % 17u;
            unsigned w = t / 17u;
            unsigned hl = p / 3u;
            unsigned wl = p - hl * 3u;
            float val;
            if (c == 16u) {
                val = 1.0f;
            } else {
                // x[w + wl - 1] lives at lds index 4 + w + wl - 1 = 3 + w + wl
                val = lds[(c * 3u + hl) * LROW + 3u + w + wl];
            }
            vals[k] = val;
        }
        outp[q] = make_float4(vals[0], vals[1], vals[2], vals[3]);
    }
}

extern "C" void kernel_launch(void* const* d_in, const int* in_sizes, int n_in,
                              void* d_out, int out_size, void* d_ws, size_t ws_size,
                              hipStream_t stream) {
    const float* x = (const float*)d_in[0];
    float* out = (float*)d_out;
    pve_kernel<<<NN * HH, 256, 0, stream>>>(x, out);
}

// Round 3
// 83.887 us; speedup vs baseline: 1.9109x; 1.0713x over previous
//
#include <hip/hip_runtime.h>

// PixelVectorExtractor: x (32,16,128,128) f32 ->
// out (32, 16384, 17, 9) f32 where out[n][h*128+w][c][hl*3+wl] =
//   c==16 ? 1.0f : zero-padded x[n][c][h+hl-1][w+wl-1]
//
// One block per (n, h). Stage rows h-1,h,h+1 (16 ch) in LDS with halo.
// Epilogue uses a per-block-constant descriptor table: output flat index
// pattern repeats every 612 elements (= 4 pixels, LCM of float4 and 153).

#define NN 32
#define CC 16
#define HH 128
#define WW 128
#define LROW 136                 // data x[w] at [4+w], pads at [3] and [132]
#define NFLOATS (CC * 3 * LROW)  // 6528 floats = 26112 B

__global__ __launch_bounds__(256) void pve_kernel(const float* __restrict__ x,
                                                  float* __restrict__ out) {
    __shared__ float lds[NFLOATS];
    __shared__ unsigned short desc[612];  // 1224 B

    // bijective XCD swizzle: 4096 blocks, 8 XCDs, 512 contiguous per XCD
    unsigned bid = blockIdx.x;
    unsigned swz = (bid & 7u) * 512u + (bid >> 3);
    unsigned n = swz >> 7;    // image
    unsigned h = swz & 127u;  // output row
    unsigned tid = threadIdx.x;

    // build descriptor table (block-invariant): entry ii in [0,612)
    // ii = (dw*17 + c)*9 + p for the 4-pixel group; desc = LDS float offset
    // relative to w0, or flag 0x8000 for the ones-channel.
    for (unsigned ii = tid; ii < 612u; ii += 256u) {
        unsigned p = ii % 9u;
        unsigned t = ii / 9u;
        unsigned c = t % 17u;
        unsigned dw = t / 17u;
        unsigned hl = p / 3u;
        unsigned wl = p - hl * 3u;
        unsigned short d;
        if (c == 16u)
            d = 0x8000u;
        else
            d = (unsigned short)((c * 3u + hl) * LROW + 3u + wl + dw);
        desc[ii] = d;
    }

    // zero the halo pad slots of all 48 (c,hl) rows
    if (tid < 48u) {
        lds[tid * LROW + 3] = 0.0f;
        lds[tid * LROW + 132] = 0.0f;
    }

    // stage: 48 rows (c*3+hl) x 32 float4, fully coalesced
#pragma unroll
    for (int j = 0; j < 6; ++j) {
        unsigned li = tid + 256u * j;  // 0..1535
        unsigned row = li >> 5;        // 0..47
        unsigned col = li & 31u;       // float4 column
        unsigned c = row / 3u;
        unsigned hl = row - c * 3u;
        int hh = (int)h + (int)hl - 1;
        float4 v = make_float4(0.f, 0.f, 0.f, 0.f);
        if ((unsigned)hh < (unsigned)HH) {
            v = reinterpret_cast<const float4*>(
                    x)[((n * CC + c) * HH + (unsigned)hh) * (WW / 4) + col];
        }
        *reinterpret_cast<float4*>(&lds[row * LROW + 4u + col * 4u]) = v;
    }
    __syncthreads();

    // write slab: 4896 float4 (= 32 groups of 153), contiguous
    unsigned base = (n * 16384u + h * 128u) * 153u;
    float4* outp = reinterpret_cast<float4*>(out + base);
#pragma unroll 4
    for (unsigned q = tid; q < 4896u; q += 256u) {
        unsigned g = q / 153u;  // 4-pixel group (0..31)
        unsigned qm = q - g * 153u;
        unsigned w0 = g * 4u;
        ushort4 d4 = *reinterpret_cast<const ushort4*>(&desc[qm * 4u]);
        float4 v;
        {
            unsigned d = d4.x;
            float t0 = lds[(d & 0x7fffu) + w0];
            v.x = (d & 0x8000u) ? 1.0f : t0;
        }
        {
            unsigned d = d4.y;
            float t0 = lds[(d & 0x7fffu) + w0];
            v.y = (d & 0x8000u) ? 1.0f : t0;
        }
        {
            unsigned d = d4.z;
            float t0 = lds[(d & 0x7fffu) + w0];
            v.z = (d & 0x8000u) ? 1.0f : t0;
        }
        {
            unsigned d = d4.w;
            float t0 = lds[(d & 0x7fffu) + w0];
            v.w = (d & 0x8000u) ? 1.0f : t0;
        }
        outp[q] = v;
    }
}

extern "C" void kernel_launch(void* const* d_in, const int* in_sizes, int n_in,
                              void* d_out, int out_size, void* d_ws, size_t ws_size,
                              hipStream_t stream) {
    const float* x = (const float*)d_in[0];
    float* out = (float*)d_out;
    pve_kernel<<<NN * HH, 256, 0, stream>>>(x, out);
}

// Round 4
// 68.809 us; speedup vs baseline: 2.3297x; 1.2191x over previous
//
#include <hip/hip_runtime.h>

// PixelVectorExtractor: x (32,16,128,128) f32 ->
// out (32, 16384, 17, 9) f32 where out[n][h*128+w][c][hl*3+wl] =
//   c==16 ? 1.0f : zero-padded x[n][c][h+hl-1][w+wl-1]
//
// One block per (n, h-pair): stage rows h0-1..h0+2 (16 ch) in LDS with halo,
// write two contiguous 78 KB output slabs via nontemporal float4 stores.
// Epilogue uses a block-invariant descriptor table (pattern repeats every
// 612 output elements = 4 pixels).

#define NN 32
#define CC 16
#define HH 128
#define WW 128
#define LROW 136                  // data x[w] at [4+w], pads at [3] and [132]
#define NROWS (CC * 4)            // 64 (c, hr) rows, hr = 0..3
#define NFLOATS (NROWS * LROW)    // 8704 floats = 34816 B

typedef float f4 __attribute__((ext_vector_type(4)));

__global__ __launch_bounds__(256) void pve_kernel(const float* __restrict__ x,
                                                  float* __restrict__ out) {
    __shared__ float lds[NFLOATS];
    __shared__ unsigned short desc[612];  // 1224 B

    // bijective XCD swizzle: 2048 blocks, 8 XCDs, 256 contiguous per XCD
    unsigned bid = blockIdx.x;
    unsigned swz = (bid & 7u) * 256u + (bid >> 3);
    unsigned n = swz >> 6;     // image
    unsigned hp = swz & 63u;   // row pair
    unsigned h0 = hp * 2u;
    unsigned tid = threadIdx.x;

    // descriptor table (block-invariant): ii = (dw*17 + c)*9 + p
    // value = LDS float offset for slab 0 (add w0 + s*LROW), flag = ones-ch
    for (unsigned ii = tid; ii < 612u; ii += 256u) {
        unsigned p = ii % 9u;
        unsigned t = ii / 9u;
        unsigned c = t % 17u;
        unsigned dw = t / 17u;
        unsigned hl = p / 3u;
        unsigned wl = p - hl * 3u;
        desc[ii] = (c == 16u)
                       ? (unsigned short)0x8000u
                       : (unsigned short)((c * 4u + hl) * LROW + 3u + wl + dw);
    }

    // zero the halo pad slots of all 64 (c,hr) rows
    if (tid < NROWS) {
        lds[tid * LROW + 3] = 0.0f;
        lds[tid * LROW + 132] = 0.0f;
    }

    // stage: 64 rows x 32 float4 = 2048 float4, 8 per thread, coalesced
#pragma unroll
    for (int j = 0; j < 8; ++j) {
        unsigned li = tid + 256u * j;  // 0..2047
        unsigned row = li >> 5;        // 0..63 = c*4 + hr
        unsigned col = li & 31u;       // float4 column
        unsigned c = row >> 2;
        unsigned hr = row & 3u;
        int hh = (int)h0 + (int)hr - 1;
        f4 v = {0.f, 0.f, 0.f, 0.f};
        if ((unsigned)hh < (unsigned)HH) {
            v = reinterpret_cast<const f4*>(
                    x)[((n * CC + c) * HH + (unsigned)hh) * (WW / 4) + col];
        }
        *reinterpret_cast<f4*>(&lds[row * LROW + 4u + col * 4u]) = v;
    }
    __syncthreads();

    // two slabs of 4896 float4 each, contiguous, nontemporal
#pragma unroll
    for (unsigned s = 0; s < 2u; ++s) {
        unsigned base = (n * 16384u + (h0 + s) * 128u) * 153u;
        f4* outp = reinterpret_cast<f4*>(out + base);
        unsigned sofs = s * LROW;
#pragma unroll 4
        for (unsigned q = tid; q < 4896u; q += 256u) {
            unsigned g = q / 153u;  // 4-pixel group (0..31)
            unsigned qm = q - g * 153u;
            unsigned wo = g * 4u + sofs;
            ushort4 d4 = *reinterpret_cast<const ushort4*>(&desc[qm * 4u]);
            f4 v;
            v.x = (d4.x & 0x8000u) ? 1.0f : lds[(d4.x & 0x7fffu) + wo];
            v.y = (d4.y & 0x8000u) ? 1.0f : lds[(d4.y & 0x7fffu) + wo];
            v.z = (d4.z & 0x8000u) ? 1.0f : lds[(d4.z & 0x7fffu) + wo];
            v.w = (d4.w & 0x8000u) ? 1.0f : lds[(d4.w & 0x7fffu) + wo];
            __builtin_nontemporal_store(v, &outp[q]);
        }
    }
}

extern "C" void kernel_launch(void* const* d_in, const int* in_sizes, int n_in,
                              void* d_out, int out_size, void* d_ws, size_t ws_size,
                              hipStream_t stream) {
    const float* x = (const float*)d_in[0];
    float* out = (float*)d_out;
    pve_kernel<<<NN * HH / 2, 256, 0, stream>>>(x, out);
}

// Round 5
// 67.888 us; speedup vs baseline: 2.3613x; 1.0136x over previous
//
#include <hip/hip_runtime.h>

// PixelVectorExtractor: x (32,16,128,128) f32 ->
// out (32, 16384, 17, 9) f32 where out[n][h*128+w][c][hl*3+wl] =
//   c==16 ? 1.0f : zero-padded x[n][c][h+hl-1][w+wl-1]
//
// One block per (n, h-pair). Stage rows h0-1..h0+2 of 16 channels in LDS
// (bank-skewed layout) plus a materialized all-ones channel 16. Epilogue
// reads u32 byte-offset descriptors (pattern repeats every 612 outputs =
// 4 pixels) and does uniform add+ds_read_b32 per value -> NT float4 store.
//
// Layout: float index of (c, hr, w') = c*564 + hr*140 + 4 + w'
//   564 mod 32 = 20, 140 mod 32 = 12  -> banks spread (old 544 mod 32 = 0
//   put every channel on the same bank -> ~4-way conflicts).
//   Halo pads at [3] (w'=-1) and [132] (w'=128), zeroed.

#define NN 32
#define CC 16
#define HH 128
#define WW 128
#define RSTRIDE 140              // floats per (c,hr) row
#define CSTRIDE 564              // floats per channel (4 rows + 4 skew)
#define NFLOATS (17 * CSTRIDE)   // 9588 floats = 38352 B

typedef float f4 __attribute__((ext_vector_type(4)));

__global__ __launch_bounds__(256) void pve_kernel(const float* __restrict__ x,
                                                  float* __restrict__ out) {
    __shared__ float lds[NFLOATS];
    __shared__ unsigned desc[612];  // byte offsets, 2448 B

    // bijective XCD swizzle: 2048 blocks, 8 XCDs, 256 contiguous per XCD
    unsigned bid = blockIdx.x;
    unsigned swz = (bid & 7u) * 256u + (bid >> 3);
    unsigned n = swz >> 6;    // image
    unsigned hp = swz & 63u;  // row pair
    unsigned h0 = hp * 2u;
    unsigned tid = threadIdx.x;

    // descriptor table (block-invariant): ii = (dw*17 + c)*9 + p,
    // value = byte offset of (c, hl, 3 + wl + dw); add g*16 + s*560 at use.
    for (unsigned ii = tid; ii < 612u; ii += 256u) {
        unsigned p = ii % 9u;
        unsigned t = ii / 9u;
        unsigned c = t % 17u;
        unsigned dw = t / 17u;
        unsigned hl = p / 3u;
        unsigned wl = p - hl * 3u;
        desc[ii] = (c * CSTRIDE + hl * RSTRIDE + 3u + wl + dw) * 4u;
    }

    // ones channel: fill channel 16 region with 1.0f
    for (unsigned li = tid; li < CSTRIDE; li += 256u)
        lds[16u * CSTRIDE + li] = 1.0f;

    // zero halo pads of the 64 real (c,hr) rows
    if (tid < 64u) {
        unsigned c = tid >> 2, hr = tid & 3u;
        lds[c * CSTRIDE + hr * RSTRIDE + 3] = 0.0f;
        lds[c * CSTRIDE + hr * RSTRIDE + 132] = 0.0f;
    }

    // stage: 64 rows x 32 float4 = 2048 float4, 8 per thread, coalesced
#pragma unroll
    for (int j = 0; j < 8; ++j) {
        unsigned li = tid + 256u * j;  // 0..2047
        unsigned row = li >> 5;        // 0..63 = c*4 + hr
        unsigned col = li & 31u;       // float4 column
        unsigned c = row >> 2;
        unsigned hr = row & 3u;
        int hh = (int)h0 + (int)hr - 1;
        f4 v = {0.f, 0.f, 0.f, 0.f};
        if ((unsigned)hh < (unsigned)HH) {
            v = reinterpret_cast<const f4*>(
                    x)[((n * CC + c) * HH + (unsigned)hh) * (WW / 4) + col];
        }
        *reinterpret_cast<f4*>(&lds[c * CSTRIDE + hr * RSTRIDE + 4u + col * 4u]) = v;
    }
    __syncthreads();

    const char* ldsb = reinterpret_cast<const char*>(lds);

    // two slabs of 4896 float4 each (32 groups of 153), contiguous, NT stores
#pragma unroll
    for (unsigned s = 0; s < 2u; ++s) {
        unsigned base = (n * 16384u + (h0 + s) * 128u) * 153u;
        f4* outp = reinterpret_cast<f4*>(out + base);
        unsigned sofs = s * (RSTRIDE * 4u);  // slab row shift, bytes
#pragma unroll 2
        for (unsigned q = tid; q < 4896u; q += 256u) {
            unsigned g = q / 153u;  // 4-pixel group (0..31)
            unsigned qm = q - g * 153u;
            unsigned wo = g * 16u + sofs;  // byte offset add-on
            uint4 d4 = *reinterpret_cast<const uint4*>(&desc[qm * 4u]);
            f4 v;
            v.x = *reinterpret_cast<const float*>(ldsb + (d4.x + wo));
            v.y = *reinterpret_cast<const float*>(ldsb + (d4.y + wo));
            v.z = *reinterpret_cast<const float*>(ldsb + (d4.z + wo));
            v.w = *reinterpret_cast<const float*>(ldsb + (d4.w + wo));
            __builtin_nontemporal_store(v, &outp[q]);
        }
    }
}

extern "C" void kernel_launch(void* const* d_in, const int* in_sizes, int n_in,
                              void* d_out, int out_size, void* d_ws, size_t ws_size,
                              hipStream_t stream) {
    const float* x = (const float*)d_in[0];
    float* out = (float*)d_out;
    pve_kernel<<<NN * HH / 2, 256, 0, stream>>>(x, out);
}